// Round 5
// baseline (721.260 us; speedup 1.0000x reference)
//
#include <hip/hip_runtime.h>

#define N_NODES 100000
#define N_EDGES 1200000
#define NB 391              // buckets of 256 dst nodes: ceil(100000/256)

// Workspace layout (bytes), total ~48.8 MB:
//   row_ptr : [0, 400896)             100001 int
//   counts  : [400896, 801280)        100000 int (node in-degree histogram)
//   blk     : [801280, 801792)        scan block sums (98 int)
//   cursors : [801792, 803456)        391 int bucket cursors (padded)
//   pairs   : [803456, 5603456)       1200000 uint packed (src<<8)|(dst&255), bucket-grouped
//   sorted  : [5603456, 10403456)     1200000 int src ids grouped by dst
//   y1/y2   : [10403456, 23203456)    y1: bf16[100000*64]; reused as y2: f32[100000*16]
//   h1      : [23203456, 48803456)    f32[100000*64]; z1 then relu(z1+mean) in place
#define OFF_ROWPTR 0
#define OFF_COUNTS 400896
#define OFF_BLK    801280
#define OFF_CURS   801792
#define OFF_PAIRS  803456
#define OFF_SORTED 5603456
#define OFF_Y1     10403456
#define OFF_H1     23203456

__device__ __forceinline__ unsigned short f2bf(float f) {
    unsigned u = __float_as_uint(f);
    unsigned r = (u + 0x7fffu + ((u >> 16) & 1u)) >> 16;   // RNE
    return (unsigned short)r;
}

// ---- CSR build ----

__global__ __launch_bounds__(256) void hist_kernel(
    const int* __restrict__ dst, int* __restrict__ counts)
{
    int e = blockIdx.x * 256 + threadIdx.x;
    if (e < N_EDGES) atomicAdd(&counts[dst[e]], 1);
}

__global__ __launch_bounds__(1024) void scan_blocks_kernel(
    const int* __restrict__ counts, int* __restrict__ row_ptr, int* __restrict__ blk_sums)
{
    __shared__ int s[1024];
    int i = blockIdx.x * 1024 + threadIdx.x;
    int v = (i < N_NODES) ? counts[i] : 0;
    s[threadIdx.x] = v;
    __syncthreads();
    for (int off = 1; off < 1024; off <<= 1) {
        int t = (threadIdx.x >= off) ? s[threadIdx.x - off] : 0;
        __syncthreads();
        s[threadIdx.x] += t;
        __syncthreads();
    }
    if (i < N_NODES) row_ptr[i] = s[threadIdx.x] - v;   // exclusive, block-local
    if (threadIdx.x == 1023) blk_sums[blockIdx.x] = s[1023];
}

__global__ __launch_bounds__(128) void scan_tops_kernel(int* __restrict__ blk_sums, int nblk)
{
    __shared__ int s[128];
    int v = (threadIdx.x < nblk) ? blk_sums[threadIdx.x] : 0;
    s[threadIdx.x] = v;
    __syncthreads();
    for (int off = 1; off < 128; off <<= 1) {
        int t = (threadIdx.x >= off) ? s[threadIdx.x - off] : 0;
        __syncthreads();
        s[threadIdx.x] += t;
        __syncthreads();
    }
    if (threadIdx.x < nblk) blk_sums[threadIdx.x] = s[threadIdx.x] - v;  // exclusive
}

// Finalize row_ptr AND snapshot per-bucket cursors (cursor[b] = row_ptr[b*256]).
__global__ __launch_bounds__(256) void add_offsets_kernel(
    int* __restrict__ row_ptr, int* __restrict__ cursors, const int* __restrict__ blk_sums)
{
    int i = blockIdx.x * 256 + threadIdx.x;
    if (i < N_NODES) {
        int r = row_ptr[i] + blk_sums[i >> 10];
        row_ptr[i] = r;
        if ((i & 255) == 0) cursors[i >> 8] = r;
    }
    if (i == 0) row_ptr[N_NODES] = N_EDGES;
}

// Phase 1: scatter packed (src<<8)|(dst&255) into bucket-contiguous regions.
// Per-bucket writes are dense -> full-line writebacks (no 16x amplification).
__global__ __launch_bounds__(256) void bucket_scatter_kernel(
    const int* __restrict__ src, const int* __restrict__ dst,
    int* __restrict__ cursors, unsigned* __restrict__ pairs)
{
    int e = blockIdx.x * 256 + threadIdx.x;
    if (e < N_EDGES) {
        int d = dst[e];
        int pos = atomicAdd(&cursors[d >> 8], 1);
        pairs[pos] = ((unsigned)src[e] << 8) | (unsigned)(d & 255);
    }
}

// Phase 2: one block per bucket. LDS per-node cursors; writes stay inside the
// bucket's ~12 KB window of sorted_src (L2-local, coalescing writebacks).
__global__ __launch_bounds__(256) void bucket_fill_kernel(
    const unsigned* __restrict__ pairs,
    const int* __restrict__ row_ptr,
    int* __restrict__ sorted_src)
{
    __shared__ int cur[256];
    const int b = blockIdx.x;
    const int base_node = b << 8;
    const int nn = min(256, N_NODES - base_node);
    if (threadIdx.x < nn) cur[threadIdx.x] = row_ptr[base_node + threadIdx.x];
    __syncthreads();

    const int bucket_base = row_ptr[base_node];
    const int bucket_end  = row_ptr[base_node + nn];
    for (int e = bucket_base + threadIdx.x; e < bucket_end; e += 256) {
        unsigned u = pairs[e];
        int pos = atomicAdd(&cur[u & 255u], 1);
        sorted_src[pos] = (int)(u >> 8);
    }
}

// ---- Dense transforms (linearity: aggregate AFTER transform) ----

// y1 = x @ W1n  (bf16 out), z1 = x @ W1s + b1  (f32, written into h1 buffer)
__global__ __launch_bounds__(256) void dense1_kernel(
    const float* __restrict__ x,
    const float* __restrict__ Wn, const float* __restrict__ Ws,
    const float* __restrict__ b,
    unsigned short* __restrict__ y1, float* __restrict__ z1)
{
    __shared__ float sWn[64 * 64];
    __shared__ float sWs[64 * 64];
    __shared__ float sb[64];
    for (int i = threadIdx.x; i < 64 * 64; i += 256) { sWn[i] = Wn[i]; sWs[i] = Ws[i]; }
    if (threadIdx.x < 64) sb[threadIdx.x] = b[threadIdx.x];
    __syncthreads();

    int n = blockIdx.x * 256 + threadIdx.x;
    if (n >= N_NODES) return;

    float xr[64];
    const float4* xp = (const float4*)(x + (size_t)n * 64);
#pragma unroll
    for (int k4 = 0; k4 < 16; ++k4) {
        float4 v = xp[k4];
        xr[4 * k4 + 0] = v.x; xr[4 * k4 + 1] = v.y;
        xr[4 * k4 + 2] = v.z; xr[4 * k4 + 3] = v.w;
    }

    uint4* yp = (uint4*)(y1 + (size_t)n * 64);
    float4* zp = (float4*)(z1 + (size_t)n * 64);
#pragma unroll 1
    for (int j0 = 0; j0 < 64; j0 += 8) {
        float ay[8], az[8];
#pragma unroll
        for (int jj = 0; jj < 8; ++jj) { ay[jj] = 0.f; az[jj] = sb[j0 + jj]; }
#pragma unroll
        for (int k = 0; k < 64; ++k) {
            float xv = xr[k];
#pragma unroll
            for (int jj = 0; jj < 8; ++jj) {
                ay[jj] += xv * sWn[k * 64 + j0 + jj];
                az[jj] += xv * sWs[k * 64 + j0 + jj];
            }
        }
        uint4 pk;
        pk.x = (unsigned)f2bf(ay[0]) | ((unsigned)f2bf(ay[1]) << 16);
        pk.y = (unsigned)f2bf(ay[2]) | ((unsigned)f2bf(ay[3]) << 16);
        pk.z = (unsigned)f2bf(ay[4]) | ((unsigned)f2bf(ay[5]) << 16);
        pk.w = (unsigned)f2bf(ay[6]) | ((unsigned)f2bf(ay[7]) << 16);
        yp[j0 / 8] = pk;
        zp[j0 / 4 + 0] = make_float4(az[0], az[1], az[2], az[3]);
        zp[j0 / 4 + 1] = make_float4(az[4], az[5], az[6], az[7]);
    }
}

// y2 = h1 @ W2n (f32), z2 = h1 @ W2s + b2  written directly into d_out
__global__ __launch_bounds__(256) void dense2_kernel(
    const float* __restrict__ h1,
    const float* __restrict__ Wn, const float* __restrict__ Ws,
    const float* __restrict__ b,
    float* __restrict__ y2, float* __restrict__ out)
{
    __shared__ float sWn[64 * 16];
    __shared__ float sWs[64 * 16];
    __shared__ float sb[16];
    for (int i = threadIdx.x; i < 64 * 16; i += 256) { sWn[i] = Wn[i]; sWs[i] = Ws[i]; }
    if (threadIdx.x < 16) sb[threadIdx.x] = b[threadIdx.x];
    __syncthreads();

    int n = blockIdx.x * 256 + threadIdx.x;
    if (n >= N_NODES) return;

    float hr[64];
    const float4* hp = (const float4*)(h1 + (size_t)n * 64);
#pragma unroll
    for (int k4 = 0; k4 < 16; ++k4) {
        float4 v = hp[k4];
        hr[4 * k4 + 0] = v.x; hr[4 * k4 + 1] = v.y;
        hr[4 * k4 + 2] = v.z; hr[4 * k4 + 3] = v.w;
    }

    float ay[16], az[16];
#pragma unroll
    for (int j = 0; j < 16; ++j) { ay[j] = 0.f; az[j] = sb[j]; }
#pragma unroll
    for (int k = 0; k < 64; ++k) {
        float hv = hr[k];
#pragma unroll
        for (int j = 0; j < 16; ++j) {
            ay[j] += hv * sWn[k * 16 + j];
            az[j] += hv * sWs[k * 16 + j];
        }
    }
    float4* yp = (float4*)(y2 + (size_t)n * 16);
    float4* op = (float4*)(out + (size_t)n * 16);
#pragma unroll
    for (int q = 0; q < 4; ++q) {
        yp[q] = make_float4(ay[4 * q], ay[4 * q + 1], ay[4 * q + 2], ay[4 * q + 3]);
        op[q] = make_float4(az[4 * q], az[4 * q + 1], az[4 * q + 2], az[4 * q + 3]);
    }
}

// ---- Pure gathers (no weights -> low VGPR -> high occupancy) ----

// h1[n] = relu(h1[n] + mean(y1[src])), y1 bf16 rows of 64 (128 B)
__global__ __launch_bounds__(256) void gather1_kernel(
    const unsigned short* __restrict__ y1,
    const int* __restrict__ row_ptr,
    const int* __restrict__ sorted_src,
    float* __restrict__ h1)
{
    const int w = threadIdx.x >> 6;
    const int lane = threadIdx.x & 63;
    const int n = blockIdx.x * 4 + w;          // grid 25000 -> exact
    const int group = lane >> 4;
    const int fl = lane & 15;

    const int start = row_ptr[n];
    const int deg = row_ptr[n + 1] - start;

    float a0 = 0.f, a1 = 0.f, a2 = 0.f, a3 = 0.f;
    for (int base = 0; base < deg; base += 64) {
        const int m = min(64, deg - base);
        int eid = 0;
        if (lane < m) eid = sorted_src[start + base + lane];
        for (int jj = 0; jj < m; jj += 4) {
            const int idx = jj + group;
            const int s = __shfl(eid, idx);
            if (idx < m) {
                uint2 raw = ((const uint2*)(y1 + (size_t)s * 64))[fl];
                a0 += __uint_as_float(raw.x << 16);
                a1 += __uint_as_float(raw.x & 0xffff0000u);
                a2 += __uint_as_float(raw.y << 16);
                a3 += __uint_as_float(raw.y & 0xffff0000u);
            }
        }
    }
    a0 += __shfl_xor(a0, 16); a1 += __shfl_xor(a1, 16);
    a2 += __shfl_xor(a2, 16); a3 += __shfl_xor(a3, 16);
    a0 += __shfl_xor(a0, 32); a1 += __shfl_xor(a1, 32);
    a2 += __shfl_xor(a2, 32); a3 += __shfl_xor(a3, 32);

    const float invd = 1.0f / (float)max(deg, 1);
    if (group == 0) {
        float4* hp = (float4*)(h1 + (size_t)n * 64);
        float4 z = hp[fl];
        hp[fl] = make_float4(fmaxf(z.x + a0 * invd, 0.f),
                             fmaxf(z.y + a1 * invd, 0.f),
                             fmaxf(z.z + a2 * invd, 0.f),
                             fmaxf(z.w + a3 * invd, 0.f));
    }
}

// out[n] += mean(y2[src]), y2 f32 rows of 16 (64 B); 16 edges in flight per wave.
__global__ __launch_bounds__(256) void gather2_kernel(
    const float* __restrict__ y2,
    const int* __restrict__ row_ptr,
    const int* __restrict__ sorted_src,
    float* __restrict__ out)
{
    const int w = threadIdx.x >> 6;
    const int lane = threadIdx.x & 63;
    const int n = blockIdx.x * 4 + w;
    const int group = lane >> 2;
    const int fl = lane & 3;

    const int start = row_ptr[n];
    const int deg = row_ptr[n + 1] - start;

    float4 acc = make_float4(0.f, 0.f, 0.f, 0.f);
    for (int base = 0; base < deg; base += 64) {
        const int m = min(64, deg - base);
        int eid = 0;
        if (lane < m) eid = sorted_src[start + base + lane];
        for (int jj = 0; jj < m; jj += 16) {
            const int idx = jj + group;
            const int s = __shfl(eid, idx);
            if (idx < m) {
                float4 v = ((const float4*)(y2 + (size_t)s * 16))[fl];
                acc.x += v.x; acc.y += v.y; acc.z += v.z; acc.w += v.w;
            }
        }
    }
#pragma unroll
    for (int d = 4; d <= 32; d <<= 1) {
        acc.x += __shfl_xor(acc.x, d); acc.y += __shfl_xor(acc.y, d);
        acc.z += __shfl_xor(acc.z, d); acc.w += __shfl_xor(acc.w, d);
    }
    const float invd = 1.0f / (float)max(deg, 1);
    if (lane < 4) {
        float4* op = (float4*)(out + (size_t)n * 16);
        float4 z = op[fl];
        op[fl] = make_float4(z.x + acc.x * invd, z.y + acc.y * invd,
                             z.z + acc.z * invd, z.w + acc.w * invd);
    }
}

extern "C" void kernel_launch(void* const* d_in, const int* in_sizes, int n_in,
                              void* d_out, int out_size, void* d_ws, size_t ws_size,
                              hipStream_t stream) {
    const float* x   = (const float*)d_in[0];
    const int*   src = (const int*)d_in[1];
    const int*   dst = (const int*)d_in[2];
    const float* W1s = (const float*)d_in[3];
    const float* W1n = (const float*)d_in[4];
    const float* b1  = (const float*)d_in[5];
    const float* W2s = (const float*)d_in[6];
    const float* W2n = (const float*)d_in[7];
    const float* b2  = (const float*)d_in[8];
    float* out = (float*)d_out;

    char* ws = (char*)d_ws;
    int* row_ptr    = (int*)(ws + OFF_ROWPTR);
    int* counts     = (int*)(ws + OFF_COUNTS);
    int* blk_sums   = (int*)(ws + OFF_BLK);
    int* cursors    = (int*)(ws + OFF_CURS);
    unsigned* pairs = (unsigned*)(ws + OFF_PAIRS);
    int* sorted_src = (int*)(ws + OFF_SORTED);
    unsigned short* y1 = (unsigned short*)(ws + OFF_Y1);
    float* y2       = (float*)(ws + OFF_Y1);   // reuses y1 space after gather1
    float* h1       = (float*)(ws + OFF_H1);

    hipMemsetAsync(counts, 0, N_NODES * sizeof(int), stream);

    const int edge_blocks = (N_EDGES + 255) / 256;
    const int nscan_blocks = (N_NODES + 1023) / 1024;   // 98
    const int node_blocks = (N_NODES + 255) / 256;      // 391
    const int wave_blocks = N_NODES / 4;                // 25000

    // CSR build (bucketed two-phase fill)
    hist_kernel<<<edge_blocks, 256, 0, stream>>>(dst, counts);
    scan_blocks_kernel<<<nscan_blocks, 1024, 0, stream>>>(counts, row_ptr, blk_sums);
    scan_tops_kernel<<<1, 128, 0, stream>>>(blk_sums, nscan_blocks);
    add_offsets_kernel<<<node_blocks, 256, 0, stream>>>(row_ptr, cursors, blk_sums);
    bucket_scatter_kernel<<<edge_blocks, 256, 0, stream>>>(src, dst, cursors, pairs);
    bucket_fill_kernel<<<NB, 256, 0, stream>>>(pairs, row_ptr, sorted_src);

    // Layer 1: transform-then-aggregate
    dense1_kernel<<<node_blocks, 256, 0, stream>>>(x, W1n, W1s, b1, y1, h1);
    gather1_kernel<<<wave_blocks, 256, 0, stream>>>(y1, row_ptr, sorted_src, h1);

    // Layer 2
    dense2_kernel<<<node_blocks, 256, 0, stream>>>(h1, W2n, W2s, b2, y2, out);
    gather2_kernel<<<wave_blocks, 256, 0, stream>>>(y2, row_ptr, sorted_src, out);
}

// Round 6
// 348.950 us; speedup vs baseline: 2.0669x; 2.0669x over previous
//
#include <hip/hip_runtime.h>

#define N_NODES 100000
#define N_EDGES 1200000
#define NB 391              // buckets of 256 dst nodes: ceil(100000/256)
#define CHUNK 16384
#define NSCBLK ((N_EDGES + CHUNK - 1) / CHUNK)   // 74

// Workspace layout (bytes), total ~48.8 MB:
//   row_ptr : [0, 400896)             100001 int
//   counts  : [400896, 801280)        100000 int (node in-degree histogram)
//   blk     : [801280, 801792)        scan block sums (98 int)
//   cursors : [801792, 803456)        391 int bucket cursors (padded)
//   pairs   : [803456, 5603456)       1200000 uint packed (src<<8)|(dst&255), bucket-grouped
//   sorted  : [5603456, 10403456)     1200000 int src ids grouped by dst
//   y1/y2   : [10403456, 23203456)    y1: bf16[100000*64]; reused as y2: f32[100000*16]
//   h1      : [23203456, 48803456)    f32[100000*64]; z1 then relu(z1+mean) in place
#define OFF_ROWPTR 0
#define OFF_COUNTS 400896
#define OFF_BLK    801280
#define OFF_CURS   801792
#define OFF_PAIRS  803456
#define OFF_SORTED 5603456
#define OFF_Y1     10403456
#define OFF_H1     23203456

__device__ __forceinline__ unsigned short f2bf(float f) {
    unsigned u = __float_as_uint(f);
    unsigned r = (u + 0x7fffu + ((u >> 16) & 1u)) >> 16;   // RNE
    return (unsigned short)r;
}

// ---- CSR build ----

__global__ __launch_bounds__(256) void hist_kernel(
    const int* __restrict__ dst, int* __restrict__ counts)
{
    int e = blockIdx.x * 256 + threadIdx.x;
    if (e < N_EDGES) atomicAdd(&counts[dst[e]], 1);
}

__global__ __launch_bounds__(1024) void scan_blocks_kernel(
    const int* __restrict__ counts, int* __restrict__ row_ptr, int* __restrict__ blk_sums)
{
    __shared__ int s[1024];
    int i = blockIdx.x * 1024 + threadIdx.x;
    int v = (i < N_NODES) ? counts[i] : 0;
    s[threadIdx.x] = v;
    __syncthreads();
    for (int off = 1; off < 1024; off <<= 1) {
        int t = (threadIdx.x >= off) ? s[threadIdx.x - off] : 0;
        __syncthreads();
        s[threadIdx.x] += t;
        __syncthreads();
    }
    if (i < N_NODES) row_ptr[i] = s[threadIdx.x] - v;   // exclusive, block-local
    if (threadIdx.x == 1023) blk_sums[blockIdx.x] = s[1023];
}

__global__ __launch_bounds__(128) void scan_tops_kernel(int* __restrict__ blk_sums, int nblk)
{
    __shared__ int s[128];
    int v = (threadIdx.x < nblk) ? blk_sums[threadIdx.x] : 0;
    s[threadIdx.x] = v;
    __syncthreads();
    for (int off = 1; off < 128; off <<= 1) {
        int t = (threadIdx.x >= off) ? s[threadIdx.x - off] : 0;
        __syncthreads();
        s[threadIdx.x] += t;
        __syncthreads();
    }
    if (threadIdx.x < nblk) blk_sums[threadIdx.x] = s[threadIdx.x] - v;  // exclusive
}

// Finalize row_ptr AND snapshot per-bucket cursors (cursor[b] = row_ptr[b*256]).
__global__ __launch_bounds__(256) void add_offsets_kernel(
    int* __restrict__ row_ptr, int* __restrict__ cursors, const int* __restrict__ blk_sums)
{
    int i = blockIdx.x * 256 + threadIdx.x;
    if (i < N_NODES) {
        int r = row_ptr[i] + blk_sums[i >> 10];
        row_ptr[i] = r;
        if ((i & 255) == 0) cursors[i >> 8] = r;
    }
    if (i == 0) row_ptr[N_NODES] = N_EDGES;
}

// Phase 1: block-chunked LDS-binned scatter. Each block takes CHUNK edges,
// histograms buckets in LDS, reserves one contiguous run per bucket with a
// SINGLE global atomic (74 atomics/address total, vs 3070 per-edge before),
// then writes packed pairs into its runs (~168 B dense per run).
__global__ __launch_bounds__(256) void binned_scatter_kernel(
    const int* __restrict__ src, const int* __restrict__ dst,
    int* __restrict__ cursors, unsigned* __restrict__ pairs)
{
    __shared__ int hist[NB];
    __shared__ int base[NB];
    const int e0 = blockIdx.x * CHUNK;
    const int e1 = min(e0 + CHUNK, N_EDGES);

    for (int i = threadIdx.x; i < NB; i += 256) hist[i] = 0;
    __syncthreads();
    for (int e = e0 + threadIdx.x; e < e1; e += 256)
        atomicAdd(&hist[dst[e] >> 8], 1);
    __syncthreads();
    for (int i = threadIdx.x; i < NB; i += 256) {
        int c = hist[i];
        base[i] = (c > 0) ? atomicAdd(&cursors[i], c) : 0;
        hist[i] = 0;                       // reuse as block-local cursor
    }
    __syncthreads();
    for (int e = e0 + threadIdx.x; e < e1; e += 256) {
        int d = dst[e];
        int b = d >> 8;
        int pos = base[b] + atomicAdd(&hist[b], 1);
        pairs[pos] = ((unsigned)src[e] << 8) | (unsigned)(d & 255);
    }
}

// Phase 2: one block per bucket. LDS per-node cursors; all writes land inside
// the bucket's ~12 KB block-exclusive window of sorted_src (L2-local).
__global__ __launch_bounds__(256) void bucket_fill_kernel(
    const unsigned* __restrict__ pairs,
    const int* __restrict__ row_ptr,
    int* __restrict__ sorted_src)
{
    __shared__ int cur[256];
    const int b = blockIdx.x;
    const int base_node = b << 8;
    const int nn = min(256, N_NODES - base_node);
    if (threadIdx.x < nn) cur[threadIdx.x] = row_ptr[base_node + threadIdx.x];
    __syncthreads();

    const int bucket_base = row_ptr[base_node];
    const int bucket_end  = row_ptr[base_node + nn];
    for (int e = bucket_base + threadIdx.x; e < bucket_end; e += 256) {
        unsigned u = pairs[e];
        int pos = atomicAdd(&cur[u & 255u], 1);
        sorted_src[pos] = (int)(u >> 8);
    }
}

// ---- Dense transforms (linearity: aggregate AFTER transform) ----

// y1 = x @ W1n  (bf16 out), z1 = x @ W1s + b1  (f32, written into h1 buffer)
__global__ __launch_bounds__(256) void dense1_kernel(
    const float* __restrict__ x,
    const float* __restrict__ Wn, const float* __restrict__ Ws,
    const float* __restrict__ b,
    unsigned short* __restrict__ y1, float* __restrict__ z1)
{
    __shared__ float sWn[64 * 64];
    __shared__ float sWs[64 * 64];
    __shared__ float sb[64];
    for (int i = threadIdx.x; i < 64 * 64; i += 256) { sWn[i] = Wn[i]; sWs[i] = Ws[i]; }
    if (threadIdx.x < 64) sb[threadIdx.x] = b[threadIdx.x];
    __syncthreads();

    int n = blockIdx.x * 256 + threadIdx.x;
    if (n >= N_NODES) return;

    float xr[64];
    const float4* xp = (const float4*)(x + (size_t)n * 64);
#pragma unroll
    for (int k4 = 0; k4 < 16; ++k4) {
        float4 v = xp[k4];
        xr[4 * k4 + 0] = v.x; xr[4 * k4 + 1] = v.y;
        xr[4 * k4 + 2] = v.z; xr[4 * k4 + 3] = v.w;
    }

    uint4* yp = (uint4*)(y1 + (size_t)n * 64);
    float4* zp = (float4*)(z1 + (size_t)n * 64);
#pragma unroll 1
    for (int j0 = 0; j0 < 64; j0 += 8) {
        float ay[8], az[8];
#pragma unroll
        for (int jj = 0; jj < 8; ++jj) { ay[jj] = 0.f; az[jj] = sb[j0 + jj]; }
#pragma unroll
        for (int k = 0; k < 64; ++k) {
            float xv = xr[k];
#pragma unroll
            for (int jj = 0; jj < 8; ++jj) {
                ay[jj] += xv * sWn[k * 64 + j0 + jj];
                az[jj] += xv * sWs[k * 64 + j0 + jj];
            }
        }
        uint4 pk;
        pk.x = (unsigned)f2bf(ay[0]) | ((unsigned)f2bf(ay[1]) << 16);
        pk.y = (unsigned)f2bf(ay[2]) | ((unsigned)f2bf(ay[3]) << 16);
        pk.z = (unsigned)f2bf(ay[4]) | ((unsigned)f2bf(ay[5]) << 16);
        pk.w = (unsigned)f2bf(ay[6]) | ((unsigned)f2bf(ay[7]) << 16);
        yp[j0 / 8] = pk;
        zp[j0 / 4 + 0] = make_float4(az[0], az[1], az[2], az[3]);
        zp[j0 / 4 + 1] = make_float4(az[4], az[5], az[6], az[7]);
    }
}

// y2 = h1 @ W2n (f32), z2 = h1 @ W2s + b2  written directly into d_out
__global__ __launch_bounds__(256) void dense2_kernel(
    const float* __restrict__ h1,
    const float* __restrict__ Wn, const float* __restrict__ Ws,
    const float* __restrict__ b,
    float* __restrict__ y2, float* __restrict__ out)
{
    __shared__ float sWn[64 * 16];
    __shared__ float sWs[64 * 16];
    __shared__ float sb[16];
    for (int i = threadIdx.x; i < 64 * 16; i += 256) { sWn[i] = Wn[i]; sWs[i] = Ws[i]; }
    if (threadIdx.x < 16) sb[threadIdx.x] = b[threadIdx.x];
    __syncthreads();

    int n = blockIdx.x * 256 + threadIdx.x;
    if (n >= N_NODES) return;

    float hr[64];
    const float4* hp = (const float4*)(h1 + (size_t)n * 64);
#pragma unroll
    for (int k4 = 0; k4 < 16; ++k4) {
        float4 v = hp[k4];
        hr[4 * k4 + 0] = v.x; hr[4 * k4 + 1] = v.y;
        hr[4 * k4 + 2] = v.z; hr[4 * k4 + 3] = v.w;
    }

    float ay[16], az[16];
#pragma unroll
    for (int j = 0; j < 16; ++j) { ay[j] = 0.f; az[j] = sb[j]; }
#pragma unroll
    for (int k = 0; k < 64; ++k) {
        float hv = hr[k];
#pragma unroll
        for (int j = 0; j < 16; ++j) {
            ay[j] += hv * sWn[k * 16 + j];
            az[j] += hv * sWs[k * 16 + j];
        }
    }
    float4* yp = (float4*)(y2 + (size_t)n * 16);
    float4* op = (float4*)(out + (size_t)n * 16);
#pragma unroll
    for (int q = 0; q < 4; ++q) {
        yp[q] = make_float4(ay[4 * q], ay[4 * q + 1], ay[4 * q + 2], ay[4 * q + 3]);
        op[q] = make_float4(az[4 * q], az[4 * q + 1], az[4 * q + 2], az[4 * q + 3]);
    }
}

// ---- Pure gathers (no weights -> low VGPR -> high occupancy) ----

// h1[n] = relu(h1[n] + mean(y1[src])), y1 bf16 rows of 64 (128 B)
__global__ __launch_bounds__(256) void gather1_kernel(
    const unsigned short* __restrict__ y1,
    const int* __restrict__ row_ptr,
    const int* __restrict__ sorted_src,
    float* __restrict__ h1)
{
    const int w = threadIdx.x >> 6;
    const int lane = threadIdx.x & 63;
    const int n = blockIdx.x * 4 + w;          // grid 25000 -> exact
    const int group = lane >> 4;
    const int fl = lane & 15;

    const int start = row_ptr[n];
    const int deg = row_ptr[n + 1] - start;

    float a0 = 0.f, a1 = 0.f, a2 = 0.f, a3 = 0.f;
    for (int base = 0; base < deg; base += 64) {
        const int m = min(64, deg - base);
        int eid = 0;
        if (lane < m) eid = sorted_src[start + base + lane];
        for (int jj = 0; jj < m; jj += 4) {
            const int idx = jj + group;
            const int s = __shfl(eid, idx);
            if (idx < m) {
                uint2 raw = ((const uint2*)(y1 + (size_t)s * 64))[fl];
                a0 += __uint_as_float(raw.x << 16);
                a1 += __uint_as_float(raw.x & 0xffff0000u);
                a2 += __uint_as_float(raw.y << 16);
                a3 += __uint_as_float(raw.y & 0xffff0000u);
            }
        }
    }
    a0 += __shfl_xor(a0, 16); a1 += __shfl_xor(a1, 16);
    a2 += __shfl_xor(a2, 16); a3 += __shfl_xor(a3, 16);
    a0 += __shfl_xor(a0, 32); a1 += __shfl_xor(a1, 32);
    a2 += __shfl_xor(a2, 32); a3 += __shfl_xor(a3, 32);

    const float invd = 1.0f / (float)max(deg, 1);
    if (group == 0) {
        float4* hp = (float4*)(h1 + (size_t)n * 64);
        float4 z = hp[fl];
        hp[fl] = make_float4(fmaxf(z.x + a0 * invd, 0.f),
                             fmaxf(z.y + a1 * invd, 0.f),
                             fmaxf(z.z + a2 * invd, 0.f),
                             fmaxf(z.w + a3 * invd, 0.f));
    }
}

// out[n] += mean(y2[src]), y2 f32 rows of 16 (64 B); 16 edges in flight per wave.
__global__ __launch_bounds__(256) void gather2_kernel(
    const float* __restrict__ y2,
    const int* __restrict__ row_ptr,
    const int* __restrict__ sorted_src,
    float* __restrict__ out)
{
    const int w = threadIdx.x >> 6;
    const int lane = threadIdx.x & 63;
    const int n = blockIdx.x * 4 + w;
    const int group = lane >> 2;
    const int fl = lane & 3;

    const int start = row_ptr[n];
    const int deg = row_ptr[n + 1] - start;

    float4 acc = make_float4(0.f, 0.f, 0.f, 0.f);
    for (int base = 0; base < deg; base += 64) {
        const int m = min(64, deg - base);
        int eid = 0;
        if (lane < m) eid = sorted_src[start + base + lane];
        for (int jj = 0; jj < m; jj += 16) {
            const int idx = jj + group;
            const int s = __shfl(eid, idx);
            if (idx < m) {
                float4 v = ((const float4*)(y2 + (size_t)s * 16))[fl];
                acc.x += v.x; acc.y += v.y; acc.z += v.z; acc.w += v.w;
            }
        }
    }
#pragma unroll
    for (int d = 4; d <= 32; d <<= 1) {
        acc.x += __shfl_xor(acc.x, d); acc.y += __shfl_xor(acc.y, d);
        acc.z += __shfl_xor(acc.z, d); acc.w += __shfl_xor(acc.w, d);
    }
    const float invd = 1.0f / (float)max(deg, 1);
    if (lane < 4) {
        float4* op = (float4*)(out + (size_t)n * 16);
        float4 z = op[fl];
        op[fl] = make_float4(z.x + acc.x * invd, z.y + acc.y * invd,
                             z.z + acc.z * invd, z.w + acc.w * invd);
    }
}

extern "C" void kernel_launch(void* const* d_in, const int* in_sizes, int n_in,
                              void* d_out, int out_size, void* d_ws, size_t ws_size,
                              hipStream_t stream) {
    const float* x   = (const float*)d_in[0];
    const int*   src = (const int*)d_in[1];
    const int*   dst = (const int*)d_in[2];
    const float* W1s = (const float*)d_in[3];
    const float* W1n = (const float*)d_in[4];
    const float* b1  = (const float*)d_in[5];
    const float* W2s = (const float*)d_in[6];
    const float* W2n = (const float*)d_in[7];
    const float* b2  = (const float*)d_in[8];
    float* out = (float*)d_out;

    char* ws = (char*)d_ws;
    int* row_ptr    = (int*)(ws + OFF_ROWPTR);
    int* counts     = (int*)(ws + OFF_COUNTS);
    int* blk_sums   = (int*)(ws + OFF_BLK);
    int* cursors    = (int*)(ws + OFF_CURS);
    unsigned* pairs = (unsigned*)(ws + OFF_PAIRS);
    int* sorted_src = (int*)(ws + OFF_SORTED);
    unsigned short* y1 = (unsigned short*)(ws + OFF_Y1);
    float* y2       = (float*)(ws + OFF_Y1);   // reuses y1 space after gather1
    float* h1       = (float*)(ws + OFF_H1);

    hipMemsetAsync(counts, 0, N_NODES * sizeof(int), stream);

    const int edge_blocks = (N_EDGES + 255) / 256;
    const int nscan_blocks = (N_NODES + 1023) / 1024;   // 98
    const int node_blocks = (N_NODES + 255) / 256;      // 391
    const int wave_blocks = N_NODES / 4;                // 25000

    // CSR build (chunk-binned two-phase fill)
    hist_kernel<<<edge_blocks, 256, 0, stream>>>(dst, counts);
    scan_blocks_kernel<<<nscan_blocks, 1024, 0, stream>>>(counts, row_ptr, blk_sums);
    scan_tops_kernel<<<1, 128, 0, stream>>>(blk_sums, nscan_blocks);
    add_offsets_kernel<<<node_blocks, 256, 0, stream>>>(row_ptr, cursors, blk_sums);
    binned_scatter_kernel<<<NSCBLK, 256, 0, stream>>>(src, dst, cursors, pairs);
    bucket_fill_kernel<<<NB, 256, 0, stream>>>(pairs, row_ptr, sorted_src);

    // Layer 1: transform-then-aggregate
    dense1_kernel<<<node_blocks, 256, 0, stream>>>(x, W1n, W1s, b1, y1, h1);
    gather1_kernel<<<wave_blocks, 256, 0, stream>>>(y1, row_ptr, sorted_src, h1);

    // Layer 2
    dense2_kernel<<<node_blocks, 256, 0, stream>>>(h1, W2n, W2s, b2, y2, out);
    gather2_kernel<<<wave_blocks, 256, 0, stream>>>(y2, row_ptr, sorted_src, out);
}

// Round 7
// 302.434 us; speedup vs baseline: 2.3848x; 1.1538x over previous
//
#include <hip/hip_runtime.h>

#define N_NODES 100000
#define N_EDGES 1200000
#define NB 391                    // buckets of 256 dst nodes
#define CHUNK_E 4096
#define NBLK_E 293                // ceil(N_EDGES / CHUNK_E)
#define TOT_H (NB * NBLK_E)       // 114563
#define NSB2 ((TOT_H + 1023) / 1024)   // 112

// Workspace layout (bytes), total ~49.3 MB:
//   row_ptr : [0, 400896)              100001 int (written by bucket_fill_plus)
//   hist_g  : [400896, 859648)         NB*NBLK_E int, bucket-major
//   hs_scan : [859648, 1318400)        exclusive block-local scan of hist_g
//   blk2    : [1318400, 1318912)       112 int scan block sums
//   pairs   : [1318912, 6118912)       1200000 uint packed (src<<8)|(dst&255)
//   sorted  : [6118912, 10918912)      1200000 int src ids grouped by dst
//   y1/y2   : [10918912, 23718912)     y1: bf16[100000*64]; reused as y2: f32[100000*16]
//   h1      : [23718912, 49318912)     f32[100000*64]; z1 then relu(z1+mean) in place
#define OFF_ROWPTR 0
#define OFF_HISTG  400896
#define OFF_HSCAN  859648
#define OFF_BLK2   1318400
#define OFF_PAIRS  1318912
#define OFF_SORTED 6118912
#define OFF_Y1     10918912
#define OFF_H1     23718912

__device__ __forceinline__ unsigned short f2bf(float f) {
    unsigned u = __float_as_uint(f);
    unsigned r = (u + 0x7fffu + ((u >> 16) & 1u)) >> 16;   // RNE
    return (unsigned short)r;
}

// ---- CSR build (atomic-free radix pass over 256-node buckets) ----

// 1) per-chunk bucket histogram -> hist_g[bucket * NBLK_E + chunk]
__global__ __launch_bounds__(256) void chunk_hist_kernel(
    const int* __restrict__ dst, int* __restrict__ hist_g)
{
    __shared__ int h[NB];
    const int e0 = blockIdx.x * CHUNK_E;
    const int e1 = min(e0 + CHUNK_E, N_EDGES);
    for (int i = threadIdx.x; i < NB; i += 256) h[i] = 0;
    __syncthreads();
    for (int e = e0 + threadIdx.x; e < e1; e += 256)
        atomicAdd(&h[dst[e] >> 8], 1);
    __syncthreads();
    for (int i = threadIdx.x; i < NB; i += 256)
        hist_g[i * NBLK_E + blockIdx.x] = h[i];
}

// 2) two-level exclusive scan over TOT_H entries
__global__ __launch_bounds__(1024) void scan2_blocks_kernel(
    const int* __restrict__ hist_g, int* __restrict__ hs_scan, int* __restrict__ blk2)
{
    __shared__ int s[1024];
    int i = blockIdx.x * 1024 + threadIdx.x;
    int v = (i < TOT_H) ? hist_g[i] : 0;
    s[threadIdx.x] = v;
    __syncthreads();
    for (int off = 1; off < 1024; off <<= 1) {
        int t = (threadIdx.x >= off) ? s[threadIdx.x - off] : 0;
        __syncthreads();
        s[threadIdx.x] += t;
        __syncthreads();
    }
    if (i < TOT_H) hs_scan[i] = s[threadIdx.x] - v;
    if (threadIdx.x == 1023) blk2[blockIdx.x] = s[1023];
}

__global__ __launch_bounds__(128) void scan2_tops_kernel(int* __restrict__ blk2)
{
    __shared__ int s[128];
    int v = (threadIdx.x < NSB2) ? blk2[threadIdx.x] : 0;
    s[threadIdx.x] = v;
    __syncthreads();
    for (int off = 1; off < 128; off <<= 1) {
        int t = (threadIdx.x >= off) ? s[threadIdx.x - off] : 0;
        __syncthreads();
        s[threadIdx.x] += t;
        __syncthreads();
    }
    if (threadIdx.x < NSB2) blk2[threadIdx.x] = s[threadIdx.x] - v;  // exclusive
}

// 3) deterministic scatter: block b writes its edges into exactly-known runs.
__global__ __launch_bounds__(256) void pair_scatter_kernel(
    const int* __restrict__ src, const int* __restrict__ dst,
    const int* __restrict__ hs_scan, const int* __restrict__ blk2,
    unsigned* __restrict__ pairs)
{
    __shared__ int base_s[NB];
    __shared__ int cur_s[NB];
    const int b = blockIdx.x;
    const int e0 = b * CHUNK_E;
    const int e1 = min(e0 + CHUNK_E, N_EDGES);

    for (int i = threadIdx.x; i < NB; i += 256) {
        int idx = i * NBLK_E + b;
        base_s[i] = hs_scan[idx] + blk2[idx >> 10];
        cur_s[i] = 0;
    }
    __syncthreads();
    for (int e = e0 + threadIdx.x; e < e1; e += 256) {
        int d = dst[e];
        int bk = d >> 8;
        int pos = base_s[bk] + atomicAdd(&cur_s[bk], 1);
        pairs[pos] = ((unsigned)src[e] << 8) | (unsigned)(d & 255);
    }
}

// 4) per-bucket: derive row_ptr (LDS hist + scan) AND fill sorted_src.
__global__ __launch_bounds__(256) void bucket_fill_plus_kernel(
    const unsigned* __restrict__ pairs,
    const int* __restrict__ hs_scan, const int* __restrict__ blk2,
    int* __restrict__ row_ptr, int* __restrict__ sorted_src)
{
    __shared__ int hist[256];
    __shared__ int sc[256];
    __shared__ int cur[256];
    const int b = blockIdx.x;
    const int t = threadIdx.x;

    int i0 = b * NBLK_E;
    const int start = hs_scan[i0] + blk2[i0 >> 10];
    int end;
    if (b == NB - 1) end = N_EDGES;
    else {
        int i1 = (b + 1) * NBLK_E;
        end = hs_scan[i1] + blk2[i1 >> 10];
    }

    hist[t] = 0;
    __syncthreads();
    for (int e = start + t; e < end; e += 256)
        atomicAdd(&hist[pairs[e] & 255u], 1);
    __syncthreads();

    // exclusive scan of 256 counts (Hillis-Steele)
    int v = hist[t];
    sc[t] = v;
    __syncthreads();
    for (int off = 1; off < 256; off <<= 1) {
        int tv = (t >= off) ? sc[t - off] : 0;
        __syncthreads();
        sc[t] += tv;
        __syncthreads();
    }
    const int excl = sc[t] - v;
    const int node = (b << 8) + t;
    if (node < N_NODES) row_ptr[node] = start + excl;
    if (b == NB - 1 && t == 0) row_ptr[N_NODES] = N_EDGES;
    cur[t] = start + excl;
    __syncthreads();

    for (int e = start + t; e < end; e += 256) {
        unsigned u = pairs[e];
        int pos = atomicAdd(&cur[u & 255u], 1);
        sorted_src[pos] = (int)(u >> 8);
    }
}

// ---- Dense transforms, output-split for occupancy ----

// grid (391, 4): block (x, jg) computes outputs [16*jg, 16*jg+16) of BOTH
// y1 = x@W1n (bf16) and z1 = x@W1s + b1 (f32, into h1 buffer).
__global__ __launch_bounds__(256) void dense1_kernel(
    const float* __restrict__ x,
    const float* __restrict__ Wn, const float* __restrict__ Ws,
    const float* __restrict__ b,
    unsigned short* __restrict__ y1, float* __restrict__ z1)
{
    __shared__ float sWn[64 * 16];
    __shared__ float sWs[64 * 16];
    __shared__ float sb[16];
    const int jg = blockIdx.y;        // 0..3
    const int j0 = jg * 16;
    for (int i = threadIdx.x; i < 64 * 16; i += 256) {
        int k = i >> 4, jj = i & 15;
        sWn[i] = Wn[k * 64 + j0 + jj];
        sWs[i] = Ws[k * 64 + j0 + jj];
    }
    if (threadIdx.x < 16) sb[threadIdx.x] = b[j0 + threadIdx.x];
    __syncthreads();

    int n = blockIdx.x * 256 + threadIdx.x;
    if (n >= N_NODES) return;

    float xr[64];
    const float4* xp = (const float4*)(x + (size_t)n * 64);
#pragma unroll
    for (int k4 = 0; k4 < 16; ++k4) {
        float4 v = xp[k4];
        xr[4 * k4 + 0] = v.x; xr[4 * k4 + 1] = v.y;
        xr[4 * k4 + 2] = v.z; xr[4 * k4 + 3] = v.w;
    }

    float ay[16], az[16];
#pragma unroll
    for (int j = 0; j < 16; ++j) { ay[j] = 0.f; az[j] = sb[j]; }
#pragma unroll
    for (int k = 0; k < 64; ++k) {
        float xv = xr[k];
#pragma unroll
        for (int j = 0; j < 16; ++j) {
            ay[j] += xv * sWn[k * 16 + j];
            az[j] += xv * sWs[k * 16 + j];
        }
    }

    uint4* yp = (uint4*)(y1 + (size_t)n * 64 + j0);      // 16 bf16 = 2 uint4
    uint4 p0, p1;
    p0.x = (unsigned)f2bf(ay[0]) | ((unsigned)f2bf(ay[1]) << 16);
    p0.y = (unsigned)f2bf(ay[2]) | ((unsigned)f2bf(ay[3]) << 16);
    p0.z = (unsigned)f2bf(ay[4]) | ((unsigned)f2bf(ay[5]) << 16);
    p0.w = (unsigned)f2bf(ay[6]) | ((unsigned)f2bf(ay[7]) << 16);
    p1.x = (unsigned)f2bf(ay[8]) | ((unsigned)f2bf(ay[9]) << 16);
    p1.y = (unsigned)f2bf(ay[10]) | ((unsigned)f2bf(ay[11]) << 16);
    p1.z = (unsigned)f2bf(ay[12]) | ((unsigned)f2bf(ay[13]) << 16);
    p1.w = (unsigned)f2bf(ay[14]) | ((unsigned)f2bf(ay[15]) << 16);
    yp[0] = p0; yp[1] = p1;

    float4* zp = (float4*)(z1 + (size_t)n * 64 + j0);
#pragma unroll
    for (int q = 0; q < 4; ++q)
        zp[q] = make_float4(az[4 * q], az[4 * q + 1], az[4 * q + 2], az[4 * q + 3]);
}

// grid (391, 2): jg=0 -> y2 = h1@W2n; jg=1 -> out = h1@W2s + b2.
__global__ __launch_bounds__(256) void dense2_kernel(
    const float* __restrict__ h1,
    const float* __restrict__ Wn, const float* __restrict__ Ws,
    const float* __restrict__ b,
    float* __restrict__ y2, float* __restrict__ out)
{
    __shared__ float sW[64 * 16];
    __shared__ float sb[16];
    const int jg = blockIdx.y;        // 0: neigh->y2, 1: self->out
    const float* W = jg ? Ws : Wn;
    for (int i = threadIdx.x; i < 64 * 16; i += 256) sW[i] = W[i];
    if (threadIdx.x < 16) sb[threadIdx.x] = jg ? b[threadIdx.x] : 0.f;
    __syncthreads();

    int n = blockIdx.x * 256 + threadIdx.x;
    if (n >= N_NODES) return;

    float hr[64];
    const float4* hp = (const float4*)(h1 + (size_t)n * 64);
#pragma unroll
    for (int k4 = 0; k4 < 16; ++k4) {
        float4 v = hp[k4];
        hr[4 * k4 + 0] = v.x; hr[4 * k4 + 1] = v.y;
        hr[4 * k4 + 2] = v.z; hr[4 * k4 + 3] = v.w;
    }

    float a[16];
#pragma unroll
    for (int j = 0; j < 16; ++j) a[j] = sb[j];
#pragma unroll
    for (int k = 0; k < 64; ++k) {
        float hv = hr[k];
#pragma unroll
        for (int j = 0; j < 16; ++j) a[j] += hv * sW[k * 16 + j];
    }

    float4* tp = (float4*)((jg ? out : y2) + (size_t)n * 16);
#pragma unroll
    for (int q = 0; q < 4; ++q)
        tp[q] = make_float4(a[4 * q], a[4 * q + 1], a[4 * q + 2], a[4 * q + 3]);
}

// ---- Pure gathers ----

// h1[n] = relu(h1[n] + mean(y1[src])), y1 bf16 rows of 64 (128 B)
__global__ __launch_bounds__(256) void gather1_kernel(
    const unsigned short* __restrict__ y1,
    const int* __restrict__ row_ptr,
    const int* __restrict__ sorted_src,
    float* __restrict__ h1)
{
    const int w = threadIdx.x >> 6;
    const int lane = threadIdx.x & 63;
    const int n = blockIdx.x * 4 + w;
    const int group = lane >> 4;
    const int fl = lane & 15;

    const int start = row_ptr[n];
    const int deg = row_ptr[n + 1] - start;

    float a0 = 0.f, a1 = 0.f, a2 = 0.f, a3 = 0.f;
    for (int base = 0; base < deg; base += 64) {
        const int m = min(64, deg - base);
        int eid = 0;
        if (lane < m) eid = sorted_src[start + base + lane];
        for (int jj = 0; jj < m; jj += 4) {
            const int idx = jj + group;
            const int s = __shfl(eid, idx);
            if (idx < m) {
                uint2 raw = ((const uint2*)(y1 + (size_t)s * 64))[fl];
                a0 += __uint_as_float(raw.x << 16);
                a1 += __uint_as_float(raw.x & 0xffff0000u);
                a2 += __uint_as_float(raw.y << 16);
                a3 += __uint_as_float(raw.y & 0xffff0000u);
            }
        }
    }
    a0 += __shfl_xor(a0, 16); a1 += __shfl_xor(a1, 16);
    a2 += __shfl_xor(a2, 16); a3 += __shfl_xor(a3, 16);
    a0 += __shfl_xor(a0, 32); a1 += __shfl_xor(a1, 32);
    a2 += __shfl_xor(a2, 32); a3 += __shfl_xor(a3, 32);

    const float invd = 1.0f / (float)max(deg, 1);
    if (group == 0) {
        float4* hp = (float4*)(h1 + (size_t)n * 64);
        float4 z = hp[fl];
        hp[fl] = make_float4(fmaxf(z.x + a0 * invd, 0.f),
                             fmaxf(z.y + a1 * invd, 0.f),
                             fmaxf(z.z + a2 * invd, 0.f),
                             fmaxf(z.w + a3 * invd, 0.f));
    }
}

// out[n] += mean(y2[src]), y2 f32 rows of 16 (64 B)
__global__ __launch_bounds__(256) void gather2_kernel(
    const float* __restrict__ y2,
    const int* __restrict__ row_ptr,
    const int* __restrict__ sorted_src,
    float* __restrict__ out)
{
    const int w = threadIdx.x >> 6;
    const int lane = threadIdx.x & 63;
    const int n = blockIdx.x * 4 + w;
    const int group = lane >> 2;
    const int fl = lane & 3;

    const int start = row_ptr[n];
    const int deg = row_ptr[n + 1] - start;

    float4 acc = make_float4(0.f, 0.f, 0.f, 0.f);
    for (int base = 0; base < deg; base += 64) {
        const int m = min(64, deg - base);
        int eid = 0;
        if (lane < m) eid = sorted_src[start + base + lane];
        for (int jj = 0; jj < m; jj += 16) {
            const int idx = jj + group;
            const int s = __shfl(eid, idx);
            if (idx < m) {
                float4 v = ((const float4*)(y2 + (size_t)s * 16))[fl];
                acc.x += v.x; acc.y += v.y; acc.z += v.z; acc.w += v.w;
            }
        }
    }
#pragma unroll
    for (int d = 4; d <= 32; d <<= 1) {
        acc.x += __shfl_xor(acc.x, d); acc.y += __shfl_xor(acc.y, d);
        acc.z += __shfl_xor(acc.z, d); acc.w += __shfl_xor(acc.w, d);
    }
    const float invd = 1.0f / (float)max(deg, 1);
    if (lane < 4) {
        float4* op = (float4*)(out + (size_t)n * 16);
        float4 z = op[fl];
        op[fl] = make_float4(z.x + acc.x * invd, z.y + acc.y * invd,
                             z.z + acc.z * invd, z.w + acc.w * invd);
    }
}

extern "C" void kernel_launch(void* const* d_in, const int* in_sizes, int n_in,
                              void* d_out, int out_size, void* d_ws, size_t ws_size,
                              hipStream_t stream) {
    const float* x   = (const float*)d_in[0];
    const int*   src = (const int*)d_in[1];
    const int*   dst = (const int*)d_in[2];
    const float* W1s = (const float*)d_in[3];
    const float* W1n = (const float*)d_in[4];
    const float* b1  = (const float*)d_in[5];
    const float* W2s = (const float*)d_in[6];
    const float* W2n = (const float*)d_in[7];
    const float* b2  = (const float*)d_in[8];
    float* out = (float*)d_out;

    char* ws = (char*)d_ws;
    int* row_ptr    = (int*)(ws + OFF_ROWPTR);
    int* hist_g     = (int*)(ws + OFF_HISTG);
    int* hs_scan    = (int*)(ws + OFF_HSCAN);
    int* blk2       = (int*)(ws + OFF_BLK2);
    unsigned* pairs = (unsigned*)(ws + OFF_PAIRS);
    int* sorted_src = (int*)(ws + OFF_SORTED);
    unsigned short* y1 = (unsigned short*)(ws + OFF_Y1);
    float* y2       = (float*)(ws + OFF_Y1);   // reuses y1 space after gather1
    float* h1       = (float*)(ws + OFF_H1);

    // CSR build: radix pass, zero global atomics
    chunk_hist_kernel<<<NBLK_E, 256, 0, stream>>>(dst, hist_g);
    scan2_blocks_kernel<<<NSB2, 1024, 0, stream>>>(hist_g, hs_scan, blk2);
    scan2_tops_kernel<<<1, 128, 0, stream>>>(blk2);
    pair_scatter_kernel<<<NBLK_E, 256, 0, stream>>>(src, dst, hs_scan, blk2, pairs);
    bucket_fill_plus_kernel<<<NB, 256, 0, stream>>>(pairs, hs_scan, blk2, row_ptr, sorted_src);

    // Layer 1
    dense1_kernel<<<dim3(391, 4), 256, 0, stream>>>(x, W1n, W1s, b1, y1, h1);
    gather1_kernel<<<N_NODES / 4, 256, 0, stream>>>(y1, row_ptr, sorted_src, h1);

    // Layer 2
    dense2_kernel<<<dim3(391, 2), 256, 0, stream>>>(h1, W2n, W2s, b2, y2, out);
    gather2_kernel<<<N_NODES / 4, 256, 0, stream>>>(y2, row_ptr, sorted_src, out);
}

// Round 8
// 247.989 us; speedup vs baseline: 2.9084x; 1.2195x over previous
//
#include <hip/hip_runtime.h>

#define N_NODES 100000
#define N_EDGES 1200000
#define NB 391                    // buckets of 256 dst nodes
#define CHUNK_E 4096
#define NBLK_E 293                // ceil(N_EDGES / CHUNK_E)
#define TOT_H (NB * NBLK_E)       // 114563
#define NSB2 ((TOT_H + 1023) / 1024)   // 112

// Workspace layout (bytes), total ~49.3 MB:
//   row_ptr : [0, 400896)              100001 int (written by bucket_fill_plus)
//   hist_g  : [400896, 859648)         NB*NBLK_E int, bucket-major
//   hs_scan : [859648, 1318400)        exclusive block-local scan of hist_g
//   blk2    : [1318400, 1318912)       112 int scan block sums
//   pairs   : [1318912, 6118912)       1200000 uint packed (src<<8)|(dst&255)
//   sorted  : [6118912, 10918912)      1200000 int src ids grouped by dst
//   y1/y2   : [10918912, 23718912)     y1: bf16[100000*64]; reused as y2: f32[100000*16]
//   h1      : [23718912, 49318912)     f32[100000*64]; z1 then relu(z1+mean) in place
#define OFF_ROWPTR 0
#define OFF_HISTG  400896
#define OFF_HSCAN  859648
#define OFF_BLK2   1318400
#define OFF_PAIRS  1318912
#define OFF_SORTED 6118912
#define OFF_Y1     10918912
#define OFF_H1     23718912

__device__ __forceinline__ unsigned short f2bf(float f) {
    unsigned u = __float_as_uint(f);
    unsigned r = (u + 0x7fffu + ((u >> 16) & 1u)) >> 16;   // RNE
    return (unsigned short)r;
}

// ---- CSR build (atomic-free radix pass over 256-node buckets) ----

__global__ __launch_bounds__(256) void chunk_hist_kernel(
    const int* __restrict__ dst, int* __restrict__ hist_g)
{
    __shared__ int h[NB];
    const int e0 = blockIdx.x * CHUNK_E;
    const int e1 = min(e0 + CHUNK_E, N_EDGES);
    for (int i = threadIdx.x; i < NB; i += 256) h[i] = 0;
    __syncthreads();
    for (int e = e0 + threadIdx.x; e < e1; e += 256)
        atomicAdd(&h[dst[e] >> 8], 1);
    __syncthreads();
    for (int i = threadIdx.x; i < NB; i += 256)
        hist_g[i * NBLK_E + blockIdx.x] = h[i];
}

__global__ __launch_bounds__(1024) void scan2_blocks_kernel(
    const int* __restrict__ hist_g, int* __restrict__ hs_scan, int* __restrict__ blk2)
{
    __shared__ int s[1024];
    int i = blockIdx.x * 1024 + threadIdx.x;
    int v = (i < TOT_H) ? hist_g[i] : 0;
    s[threadIdx.x] = v;
    __syncthreads();
    for (int off = 1; off < 1024; off <<= 1) {
        int t = (threadIdx.x >= off) ? s[threadIdx.x - off] : 0;
        __syncthreads();
        s[threadIdx.x] += t;
        __syncthreads();
    }
    if (i < TOT_H) hs_scan[i] = s[threadIdx.x] - v;
    if (threadIdx.x == 1023) blk2[blockIdx.x] = s[1023];
}

__global__ __launch_bounds__(128) void scan2_tops_kernel(int* __restrict__ blk2)
{
    __shared__ int s[128];
    int v = (threadIdx.x < NSB2) ? blk2[threadIdx.x] : 0;
    s[threadIdx.x] = v;
    __syncthreads();
    for (int off = 1; off < 128; off <<= 1) {
        int t = (threadIdx.x >= off) ? s[threadIdx.x - off] : 0;
        __syncthreads();
        s[threadIdx.x] += t;
        __syncthreads();
    }
    if (threadIdx.x < NSB2) blk2[threadIdx.x] = s[threadIdx.x] - v;  // exclusive
}

__global__ __launch_bounds__(256) void pair_scatter_kernel(
    const int* __restrict__ src, const int* __restrict__ dst,
    const int* __restrict__ hs_scan, const int* __restrict__ blk2,
    unsigned* __restrict__ pairs)
{
    __shared__ int base_s[NB];
    __shared__ int cur_s[NB];
    const int b = blockIdx.x;
    const int e0 = b * CHUNK_E;
    const int e1 = min(e0 + CHUNK_E, N_EDGES);

    for (int i = threadIdx.x; i < NB; i += 256) {
        int idx = i * NBLK_E + b;
        base_s[i] = hs_scan[idx] + blk2[idx >> 10];
        cur_s[i] = 0;
    }
    __syncthreads();
    for (int e = e0 + threadIdx.x; e < e1; e += 256) {
        int d = dst[e];
        int bk = d >> 8;
        int pos = base_s[bk] + atomicAdd(&cur_s[bk], 1);
        pairs[pos] = ((unsigned)src[e] << 8) | (unsigned)(d & 255);
    }
}

__global__ __launch_bounds__(256) void bucket_fill_plus_kernel(
    const unsigned* __restrict__ pairs,
    const int* __restrict__ hs_scan, const int* __restrict__ blk2,
    int* __restrict__ row_ptr, int* __restrict__ sorted_src)
{
    __shared__ int hist[256];
    __shared__ int sc[256];
    __shared__ int cur[256];
    const int b = blockIdx.x;
    const int t = threadIdx.x;

    int i0 = b * NBLK_E;
    const int start = hs_scan[i0] + blk2[i0 >> 10];
    int end;
    if (b == NB - 1) end = N_EDGES;
    else {
        int i1 = (b + 1) * NBLK_E;
        end = hs_scan[i1] + blk2[i1 >> 10];
    }

    hist[t] = 0;
    __syncthreads();
    for (int e = start + t; e < end; e += 256)
        atomicAdd(&hist[pairs[e] & 255u], 1);
    __syncthreads();

    int v = hist[t];
    sc[t] = v;
    __syncthreads();
    for (int off = 1; off < 256; off <<= 1) {
        int tv = (t >= off) ? sc[t - off] : 0;
        __syncthreads();
        sc[t] += tv;
        __syncthreads();
    }
    const int excl = sc[t] - v;
    const int node = (b << 8) + t;
    if (node < N_NODES) row_ptr[node] = start + excl;
    if (b == NB - 1 && t == 0) row_ptr[N_NODES] = N_EDGES;
    cur[t] = start + excl;
    __syncthreads();

    for (int e = start + t; e < end; e += 256) {
        unsigned u = pairs[e];
        int pos = atomicAdd(&cur[u & 255u], 1);
        sorted_src[pos] = (int)(u >> 8);
    }
}

// ---- Dense transforms v3: weights-in-lanes, nodes streamed through LDS ----
// dense1: grid 3125; block stages 32 x-rows (8 KB) ONCE (x fetched once from
// HBM, no cross-XCD replication). Wave w: half = w>>1 (0: y1=x@Wn bf16,
// 1: z1=x@Ws+b f32), nodes (w&1)*16..+16. Lane j holds W[:,j] in 64 VGPRs.
// Per node: 16 same-address ds_read_b128 broadcasts + 64 FMAs (4 k-partials).
__global__ __launch_bounds__(256) void dense1_kernel(
    const float* __restrict__ x,
    const float* __restrict__ Wn, const float* __restrict__ Ws,
    const float* __restrict__ b,
    unsigned short* __restrict__ y1, float* __restrict__ z1)
{
    __shared__ float sx[32 * 64];
    const int t = threadIdx.x;
    const int w = t >> 6;
    const int lane = t & 63;
    const int half = w >> 1;
    const int nsub = (w & 1) * 16;
    const int chunk = blockIdx.x * 32;

    // stage 32 rows (8 KB) coalesced
    {
        const float4* gx = (const float4*)(x + (size_t)chunk * 64);
        float4* sx4 = (float4*)sx;
        sx4[t] = gx[t];
        sx4[t + 256] = gx[t + 256];
    }

    // weight column j into registers (coalesced per k: lane j reads W[k*64+j])
    const float* W = half ? Ws : Wn;
    float wr[64];
#pragma unroll
    for (int k = 0; k < 64; ++k) wr[k] = W[k * 64 + lane];
    const float bj = half ? b[lane] : 0.f;

    __syncthreads();

#pragma unroll 1
    for (int m = 0; m < 16; ++m) {
        const int node = nsub + m;
        const float4* xr = (const float4*)(sx + node * 64);
        float a0 = 0.f, a1 = 0.f, a2 = 0.f, a3 = 0.f;
#pragma unroll
        for (int k4 = 0; k4 < 16; ++k4) {
            float4 v = xr[k4];            // broadcast ds_read_b128
            a0 += v.x * wr[4 * k4 + 0];
            a1 += v.y * wr[4 * k4 + 1];
            a2 += v.z * wr[4 * k4 + 2];
            a3 += v.w * wr[4 * k4 + 3];
        }
        const float o = (a0 + a1) + (a2 + a3) + bj;
        const size_t gn = (size_t)(chunk + node);
        if (half) z1[gn * 64 + lane] = o;
        else      y1[gn * 64 + lane] = f2bf(o);
    }
}

// dense2: same pattern, 16-col outputs. Lane: j = lane&15, g = lane>>4.
// sx rows padded to 68 floats so the 4 distinct per-group broadcast
// addresses hit distinct banks. Wave w: half = w>>1 (0: y2=h1@W2n,
// 1: out=h1@W2s+b2), nodes (w&1)*16..+16 processed 4 at a time (g).
__global__ __launch_bounds__(256) void dense2_kernel(
    const float* __restrict__ h1,
    const float* __restrict__ Wn, const float* __restrict__ Ws,
    const float* __restrict__ b,
    float* __restrict__ y2, float* __restrict__ out)
{
    __shared__ float sx[32 * 68];
    const int t = threadIdx.x;
    const int w = t >> 6;
    const int lane = t & 63;
    const int half = w >> 1;
    const int nsub = (w & 1) * 16;
    const int j = lane & 15;
    const int g = lane >> 4;
    const int chunk = blockIdx.x * 32;

    // stage 32 rows at stride 68 (17 float4 per row)
    {
        const float4* gx = (const float4*)(h1 + (size_t)chunk * 64);
        float4* sx4 = (float4*)sx;
        int r0 = t >> 4, c0 = t & 15;
        sx4[r0 * 17 + c0] = gx[t];
        sx4[(r0 + 16) * 17 + c0] = gx[t + 256];
    }

    const float* W = half ? Ws : Wn;
    float wr[64];
#pragma unroll
    for (int k = 0; k < 64; ++k) wr[k] = W[k * 16 + j];
    const float bj = half ? b[j] : 0.f;

    __syncthreads();

#pragma unroll 1
    for (int q = 0; q < 4; ++q) {
        const int node = nsub + q * 4 + g;
        const float4* xr = (const float4*)(sx + node * 68);
        float a0 = 0.f, a1 = 0.f, a2 = 0.f, a3 = 0.f;
#pragma unroll
        for (int k4 = 0; k4 < 16; ++k4) {
            float4 v = xr[k4];            // 4 distinct addrs, distinct banks
            a0 += v.x * wr[4 * k4 + 0];
            a1 += v.y * wr[4 * k4 + 1];
            a2 += v.z * wr[4 * k4 + 2];
            a3 += v.w * wr[4 * k4 + 3];
        }
        const float o = (a0 + a1) + (a2 + a3) + bj;
        const size_t gn = (size_t)(chunk + node);
        if (half) out[gn * 16 + j] = o;
        else      y2[gn * 16 + j] = o;
    }
}

// ---- Pure gathers ----

__global__ __launch_bounds__(256) void gather1_kernel(
    const unsigned short* __restrict__ y1,
    const int* __restrict__ row_ptr,
    const int* __restrict__ sorted_src,
    float* __restrict__ h1)
{
    const int w = threadIdx.x >> 6;
    const int lane = threadIdx.x & 63;
    const int n = blockIdx.x * 4 + w;
    const int group = lane >> 4;
    const int fl = lane & 15;

    const int start = row_ptr[n];
    const int deg = row_ptr[n + 1] - start;

    float a0 = 0.f, a1 = 0.f, a2 = 0.f, a3 = 0.f;
    for (int base = 0; base < deg; base += 64) {
        const int m = min(64, deg - base);
        int eid = 0;
        if (lane < m) eid = sorted_src[start + base + lane];
        for (int jj = 0; jj < m; jj += 4) {
            const int idx = jj + group;
            const int s = __shfl(eid, idx);
            if (idx < m) {
                uint2 raw = ((const uint2*)(y1 + (size_t)s * 64))[fl];
                a0 += __uint_as_float(raw.x << 16);
                a1 += __uint_as_float(raw.x & 0xffff0000u);
                a2 += __uint_as_float(raw.y << 16);
                a3 += __uint_as_float(raw.y & 0xffff0000u);
            }
        }
    }
    a0 += __shfl_xor(a0, 16); a1 += __shfl_xor(a1, 16);
    a2 += __shfl_xor(a2, 16); a3 += __shfl_xor(a3, 16);
    a0 += __shfl_xor(a0, 32); a1 += __shfl_xor(a1, 32);
    a2 += __shfl_xor(a2, 32); a3 += __shfl_xor(a3, 32);

    const float invd = 1.0f / (float)max(deg, 1);
    if (group == 0) {
        float4* hp = (float4*)(h1 + (size_t)n * 64);
        float4 z = hp[fl];
        hp[fl] = make_float4(fmaxf(z.x + a0 * invd, 0.f),
                             fmaxf(z.y + a1 * invd, 0.f),
                             fmaxf(z.z + a2 * invd, 0.f),
                             fmaxf(z.w + a3 * invd, 0.f));
    }
}

__global__ __launch_bounds__(256) void gather2_kernel(
    const float* __restrict__ y2,
    const int* __restrict__ row_ptr,
    const int* __restrict__ sorted_src,
    float* __restrict__ out)
{
    const int w = threadIdx.x >> 6;
    const int lane = threadIdx.x & 63;
    const int n = blockIdx.x * 4 + w;
    const int group = lane >> 2;
    const int fl = lane & 3;

    const int start = row_ptr[n];
    const int deg = row_ptr[n + 1] - start;

    float4 acc = make_float4(0.f, 0.f, 0.f, 0.f);
    for (int base = 0; base < deg; base += 64) {
        const int m = min(64, deg - base);
        int eid = 0;
        if (lane < m) eid = sorted_src[start + base + lane];
        for (int jj = 0; jj < m; jj += 16) {
            const int idx = jj + group;
            const int s = __shfl(eid, idx);
            if (idx < m) {
                float4 v = ((const float4*)(y2 + (size_t)s * 16))[fl];
                acc.x += v.x; acc.y += v.y; acc.z += v.z; acc.w += v.w;
            }
        }
    }
#pragma unroll
    for (int d = 4; d <= 32; d <<= 1) {
        acc.x += __shfl_xor(acc.x, d); acc.y += __shfl_xor(acc.y, d);
        acc.z += __shfl_xor(acc.z, d); acc.w += __shfl_xor(acc.w, d);
    }
    const float invd = 1.0f / (float)max(deg, 1);
    if (lane < 4) {
        float4* op = (float4*)(out + (size_t)n * 16);
        float4 z = op[fl];
        op[fl] = make_float4(z.x + acc.x * invd, z.y + acc.y * invd,
                             z.z + acc.z * invd, z.w + acc.w * invd);
    }
}

extern "C" void kernel_launch(void* const* d_in, const int* in_sizes, int n_in,
                              void* d_out, int out_size, void* d_ws, size_t ws_size,
                              hipStream_t stream) {
    const float* x   = (const float*)d_in[0];
    const int*   src = (const int*)d_in[1];
    const int*   dst = (const int*)d_in[2];
    const float* W1s = (const float*)d_in[3];
    const float* W1n = (const float*)d_in[4];
    const float* b1  = (const float*)d_in[5];
    const float* W2s = (const float*)d_in[6];
    const float* W2n = (const float*)d_in[7];
    const float* b2  = (const float*)d_in[8];
    float* out = (float*)d_out;

    char* ws = (char*)d_ws;
    int* row_ptr    = (int*)(ws + OFF_ROWPTR);
    int* hist_g     = (int*)(ws + OFF_HISTG);
    int* hs_scan    = (int*)(ws + OFF_HSCAN);
    int* blk2       = (int*)(ws + OFF_BLK2);
    unsigned* pairs = (unsigned*)(ws + OFF_PAIRS);
    int* sorted_src = (int*)(ws + OFF_SORTED);
    unsigned short* y1 = (unsigned short*)(ws + OFF_Y1);
    float* y2       = (float*)(ws + OFF_Y1);   // reuses y1 space after gather1
    float* h1       = (float*)(ws + OFF_H1);

    // CSR build: radix pass, zero global atomics
    chunk_hist_kernel<<<NBLK_E, 256, 0, stream>>>(dst, hist_g);
    scan2_blocks_kernel<<<NSB2, 1024, 0, stream>>>(hist_g, hs_scan, blk2);
    scan2_tops_kernel<<<1, 128, 0, stream>>>(blk2);
    pair_scatter_kernel<<<NBLK_E, 256, 0, stream>>>(src, dst, hs_scan, blk2, pairs);
    bucket_fill_plus_kernel<<<NB, 256, 0, stream>>>(pairs, hs_scan, blk2, row_ptr, sorted_src);

    // Layer 1
    dense1_kernel<<<3125, 256, 0, stream>>>(x, W1n, W1s, b1, y1, h1);
    gather1_kernel<<<N_NODES / 4, 256, 0, stream>>>(y1, row_ptr, sorted_src, h1);

    // Layer 2
    dense2_kernel<<<3125, 256, 0, stream>>>(h1, W2n, W2s, b2, y2, out);
    gather2_kernel<<<N_NODES / 4, 256, 0, stream>>>(y2, row_ptr, sorted_src, out);
}